// Round 2
// baseline (24.462 us; speedup 1.0000x reference)
//
#include <hip/hip_runtime.h>
#include <hip/hip_fp16.h>

#define IN_F   4096
#define OUT_F  4096
#define BATCH  32
#define NGPR   (IN_F / 8)   // 512 groups per output row
#define BN     16           // output rows per block
#define NW     8            // waves per block
#define KW     (IN_F / NW)  // 512 K per wave
#define KC     128          // K per staging chunk
#define NCH    (KW / KC)    // 4 chunks per wave
#define WPITCH 136          // bf16 elems per LDS W row (128 + 8 pad, 272B = 17*16B)

typedef float f32x4  __attribute__((ext_vector_type(4)));
typedef short short8 __attribute__((ext_vector_type(8)));

__device__ __forceinline__ unsigned short f2bf_u(float f) {
    return __builtin_bit_cast(unsigned short, (__bf16)f);   // RNE via v_cvt
}

__global__ __launch_bounds__(512, 2)
void l3b_gemm_kernel(const float* __restrict__ x,
                     const int* __restrict__ wq3,
                     const void* __restrict__ wnorm_raw,
                     const float* __restrict__ bias,
                     float* __restrict__ out)
{
    __shared__ unsigned short Wlds[NW][BN][WPITCH];   // wave-private dequant tiles
    __shared__ float red[NW][BATCH][17];              // cross-wave K-reduction

    const int tid   = threadIdx.x;
    const int w     = tid >> 6;
    const int lane  = tid & 63;
    const int nbase = blockIdx.x * BN;

    // ---- weight_norm dtype probe (deterministic, wave-uniform) ----
    // 0 = float32, 1 = float16 (raw), 2 = bfloat16
    const unsigned short* wn16  = (const unsigned short*)wnorm_raw;
    const float*          wn32  = (const float*)wnorm_raw;
    const unsigned int*   wnu32 = (const unsigned int*)wnorm_raw;
    int mode;
    {
        const unsigned short h = wn16[lane];
        const float v16 = __half2float(__builtin_bit_cast(__half, h));
        const float vbf = __builtin_bit_cast(float, (unsigned int)h << 16);
        const float v32 = wn32[lane];
        const int c16 = __popcll(__ballot(v16 > 0.0095f && v16 < 1.0005f));
        const int cbf = __popcll(__ballot(vbf > 0.0095f && vbf < 1.0005f));
        const int c32 = __popcll(__ballot(v32 > 0.0095f && v32 < 1.0005f));
        if (c16 >= c32 && c16 >= cbf) {
            mode = 1;
        } else if (c32 > cbf + 8) {
            mode = 0;
        } else if (cbf > c32 + 8) {
            mode = 2;
        } else {
            // bf16 stream vs fp32-upcast-from-fp16: the latter has 13 zero
            // low mantissa bits in every element.
            const int z = __popcll(__ballot((wnu32[lane] & 0x1FFFu) == 0u));
            mode = (z >= 48) ? 0 : 2;
        }
    }

    const int r  = lane >> 2;   // staging: row 0..15
    const int gq = lane & 3;    // staging: group-quad 0..3 (4 groups each)

    const int q  = lane >> 4;   // mfma: k-block 0..3
    const int cl = lane & 15;   // mfma: n index (B) / m index (A)

    f32x4 acc0 = {0.f, 0.f, 0.f, 0.f};
    f32x4 acc1 = {0.f, 0.f, 0.f, 0.f};

    const int kwbase = w * KW;

    for (int c = 0; c < NCH; ++c) {
        const int kc = kwbase + c * KC;

        // ---- stage 16x128 dequantized bf16 W tile into wave-private LDS ----
        {
            const int  grow = (kc >> 3) + gq * 4;                  // first group in row
            const long gid0 = (long)(nbase + r) * NGPR + grow;     // multiple of 4
            const int4* qp = reinterpret_cast<const int4*>(wq3 + gid0 * 3); // 48B-aligned
            const int4 qa = qp[0];
            const int4 qb = qp[1];
            const int4 qc = qp[2];
            const int pp[12] = {qa.x, qa.y, qa.z, qa.w,
                                qb.x, qb.y, qb.z, qb.w,
                                qc.x, qc.y, qc.z, qc.w};
            float nn[4];
            if (mode == 0) {
                const float4 nv = *reinterpret_cast<const float4*>(wn32 + gid0);
                nn[0] = nv.x; nn[1] = nv.y; nn[2] = nv.z; nn[3] = nv.w;
            } else {
                const ushort4 nv = *reinterpret_cast<const ushort4*>(wn16 + gid0);
                const unsigned short ss[4] = {nv.x, nv.y, nv.z, nv.w};
                if (mode == 1) {
                    #pragma unroll
                    for (int i = 0; i < 4; ++i)
                        nn[i] = __half2float(__builtin_bit_cast(__half, ss[i]));
                } else {
                    #pragma unroll
                    for (int i = 0; i < 4; ++i)
                        nn[i] = __builtin_bit_cast(float, (unsigned int)ss[i] << 16);
                }
            }
            #pragma unroll
            for (int u = 0; u < 4; ++u) {
                const int v = (pp[3*u] & 0xFF) | ((pp[3*u+1] & 0xFF) << 8)
                            | ((pp[3*u+2] & 0xFF) << 16);
                const float n = nn[u];
                const float a = n * (2.0f / 7.0f);   // w = q*(2n/7) - n
                union { unsigned short us[8]; uint4 q4; } pk;
                #pragma unroll
                for (int e = 0; e < 8; ++e)
                    pk.us[e] = f2bf_u(fmaf((float)((v >> (3*e)) & 7), a, -n));
                // 8 consecutive bf16 = 16B aligned store (WPITCH*2 = 272 = 17*16)
                *reinterpret_cast<uint4*>(&Wlds[w][r][(gq * 4 + u) * 8]) = pk.q4;
            }
        }
        // DS ops are in-order within a wave; tile is wave-private -> no barrier.

        // ---- 4 MFMA K-steps over the 128-wide chunk ----
        #pragma unroll
        for (int ks = 0; ks < 4; ++ks) {
            const int klocal = ks * 32 + q * 8;
            const short8 bfrag =
                *reinterpret_cast<const short8*>(&Wlds[w][cl][klocal]);
            const int kg = kc + klocal;

            const float4 a0lo = *reinterpret_cast<const float4*>(&x[cl        * IN_F + kg]);
            const float4 a0hi = *reinterpret_cast<const float4*>(&x[cl        * IN_F + kg + 4]);
            const float4 a1lo = *reinterpret_cast<const float4*>(&x[(cl + 16) * IN_F + kg]);
            const float4 a1hi = *reinterpret_cast<const float4*>(&x[(cl + 16) * IN_F + kg + 4]);

            union { unsigned short us[8]; short8 v; } A0, A1;
            A0.us[0] = f2bf_u(a0lo.x); A0.us[1] = f2bf_u(a0lo.y);
            A0.us[2] = f2bf_u(a0lo.z); A0.us[3] = f2bf_u(a0lo.w);
            A0.us[4] = f2bf_u(a0hi.x); A0.us[5] = f2bf_u(a0hi.y);
            A0.us[6] = f2bf_u(a0hi.z); A0.us[7] = f2bf_u(a0hi.w);
            A1.us[0] = f2bf_u(a1lo.x); A1.us[1] = f2bf_u(a1lo.y);
            A1.us[2] = f2bf_u(a1lo.z); A1.us[3] = f2bf_u(a1lo.w);
            A1.us[4] = f2bf_u(a1hi.x); A1.us[5] = f2bf_u(a1hi.y);
            A1.us[6] = f2bf_u(a1hi.z); A1.us[7] = f2bf_u(a1hi.w);

            acc0 = __builtin_amdgcn_mfma_f32_16x16x32_bf16(A0.v, bfrag, acc0, 0, 0, 0);
            acc1 = __builtin_amdgcn_mfma_f32_16x16x32_bf16(A1.v, bfrag, acc1, 0, 0, 0);
        }
    }

    // ---- cross-wave K-reduction + bias + store ----
    #pragma unroll
    for (int i = 0; i < 4; ++i) {
        red[w][q * 4 + i][cl]      = acc0[i];
        red[w][16 + q * 4 + i][cl] = acc1[i];
    }
    __syncthreads();
    {
        const int m  = tid >> 4;   // 0..31 (512 threads -> 32x16 outputs)
        const int nl = tid & 15;
        float s = 0.f;
        #pragma unroll
        for (int wv = 0; wv < NW; ++wv) s += red[wv][m][nl];
        out[m * OUT_F + nbase + nl] = s + bias[nbase + nl];
    }
}

extern "C" void kernel_launch(void* const* d_in, const int* in_sizes, int n_in,
                              void* d_out, int out_size, void* d_ws, size_t ws_size,
                              hipStream_t stream) {
    const float* x    = (const float*)d_in[0];
    const int*   wq3  = (const int*)d_in[1];
    const void*  wn   = (const void*)d_in[2];
    const float* bias = (const float*)d_in[3];
    float*       out  = (float*)d_out;

    l3b_gemm_kernel<<<dim3(OUT_F / BN), dim3(512), 0, stream>>>(x, wq3, wn, bias, out);
}

// Round 4
// 16.811 us; speedup vs baseline: 1.4551x; 1.4551x over previous
//
#include <hip/hip_runtime.h>
#include <hip/hip_fp16.h>

#define IN_F   4096
#define OUT_F  4096
#define BATCH  32
#define NGPR   512          // groups per output row
#define BN     16           // output rows per block
#define NW     8            // waves per block
#define QPITCH 516          // dwords per row of packed-q LDS (512 + 4 pad)
#define NPITCH 516          // dwords per row of norm LDS

typedef float f32x4  __attribute__((ext_vector_type(4)));
typedef short short8 __attribute__((ext_vector_type(8)));

__device__ __forceinline__ unsigned short f2bf_u(float f) {
    return __builtin_bit_cast(unsigned short, (__bf16)f);   // RNE via v_cvt
}

// ---- pack x[32][4096] fp32 -> A-fragment-layout bf16 in d_ws ----
// apk unit u = (a*128 + s)*64 + q*16 + cl  holds bf16 x[a*16+cl][s*32+q*8 .. +8]
// 32 rows x 512 chunks-of-8 = 16384 units -> 32 blocks x 512 threads
__global__ __launch_bounds__(512)
void pack_x_kernel(const float* __restrict__ x, unsigned short* __restrict__ apk)
{
    const int tau = blockIdx.x * 512 + threadIdx.x;   // 0..16383
    const int row = tau >> 9;                         // 0..31
    const int c   = tau & 511;                        // 8-float chunk within row
    const float4 lo = *reinterpret_cast<const float4*>(&x[row * IN_F + c * 8]);
    const float4 hi = *reinterpret_cast<const float4*>(&x[row * IN_F + c * 8 + 4]);
    union { unsigned short us[8]; uint4 v; } pk;
    pk.us[0] = f2bf_u(lo.x); pk.us[1] = f2bf_u(lo.y);
    pk.us[2] = f2bf_u(lo.z); pk.us[3] = f2bf_u(lo.w);
    pk.us[4] = f2bf_u(hi.x); pk.us[5] = f2bf_u(hi.y);
    pk.us[6] = f2bf_u(hi.z); pk.us[7] = f2bf_u(hi.w);
    const int a = row >> 4, cl = row & 15, s = c >> 2, q = c & 3;
    const int unit = (a * 128 + s) * 64 + q * 16 + cl;
    *reinterpret_cast<uint4*>(&apk[unit * 8]) = pk.v;
}

template<bool PACKED>
__global__ __launch_bounds__(512, 2)
void l3b_main(const float* __restrict__ x,
              const int* __restrict__ wq3,
              const void* __restrict__ wnorm_raw,
              const float* __restrict__ bias,
              float* __restrict__ out,
              const unsigned short* __restrict__ apk)
{
    __shared__ unsigned int qw[BN][QPITCH];   // packed 24-bit group words
    __shared__ float        nrm[BN][NPITCH];  // per-group scales (fp32)
    __shared__ float        red[NW][BATCH][17];

    const int tid   = threadIdx.x;
    const int w     = tid >> 6;
    const int lane  = tid & 63;
    const int nbase = blockIdx.x * BN;

    const int q  = lane >> 4;   // 0..3
    const int cl = lane & 15;   // 0..15

    // ---- weight_norm dtype probe (deterministic, wave-uniform) ----
    // 0 = float32, 1 = float16 (raw), 2 = bfloat16
    const unsigned short* wn16  = (const unsigned short*)wnorm_raw;
    const float*          wn32  = (const float*)wnorm_raw;
    const unsigned int*   wnu32 = (const unsigned int*)wnorm_raw;
    int mode;
    {
        const unsigned short h = wn16[lane];
        const float v16 = __half2float(__builtin_bit_cast(__half, h));
        const float vbf = __builtin_bit_cast(float, (unsigned int)h << 16);
        const float v32 = wn32[lane];
        const int c16 = __popcll(__ballot(v16 > 0.0095f && v16 < 1.0005f));
        const int cbf = __popcll(__ballot(vbf > 0.0095f && vbf < 1.0005f));
        const int c32 = __popcll(__ballot(v32 > 0.0095f && v32 < 1.0005f));
        if (c16 >= c32 && c16 >= cbf) {
            mode = 1;
        } else if (c32 > cbf + 8) {
            mode = 0;
        } else if (cbf > c32 + 8) {
            mode = 2;
        } else {
            const int z = __popcll(__ballot((wnu32[lane] & 0x1FFFu) == 0u));
            mode = (z >= 48) ? 0 : 2;
        }
    }

    // ---- stage packed q-words: 16 rows x 512 groups, 4:1 compaction ----
    {
        const int* qbase = wq3 + (long)nbase * (NGPR * 3);   // 24576 int32 region
        #pragma unroll
        for (int r2 = 0; r2 < 4; ++r2) {
            const int o = r2 * 6144 + tid * 12;              // 16B-aligned (48*t)
            const int4 ia = *reinterpret_cast<const int4*>(qbase + o);
            const int4 ib = *reinterpret_cast<const int4*>(qbase + o + 4);
            const int4 ic = *reinterpret_cast<const int4*>(qbase + o + 8);
            uint4 wd;
            wd.x = (unsigned)(ia.x | (ia.y << 8) | (ia.z << 16));
            wd.y = (unsigned)(ia.w | (ib.x << 8) | (ib.y << 16));
            wd.z = (unsigned)(ib.z | (ib.w << 8) | (ic.x << 16));
            wd.w = (unsigned)(ic.y | (ic.z << 8) | (ic.w << 16));
            const int row = r2 * 4 + (tid >> 7);
            const int col = (tid * 4) & 511;
            *reinterpret_cast<uint4*>(&qw[row][col]) = wd;
        }
    }

    // ---- stage norms -> fp32 LDS ----
    if (mode == 0) {
        const float* nb = wn32 + (long)nbase * NGPR;
        #pragma unroll
        for (int j = 0; j < 4; ++j) {
            const int e = j * 2048 + tid * 4;
            const float4 v = *reinterpret_cast<const float4*>(nb + e);
            *reinterpret_cast<float4*>(&nrm[e >> 9][e & 511]) = v;
        }
    } else {
        const unsigned short* nb = wn16 + (long)nbase * NGPR;
        #pragma unroll
        for (int j = 0; j < 4; ++j) {
            const int e = j * 2048 + tid * 4;
            const ushort4 v = *reinterpret_cast<const ushort4*>(nb + e);
            float4 f;
            if (mode == 1) {
                f.x = __half2float(__builtin_bit_cast(__half, v.x));
                f.y = __half2float(__builtin_bit_cast(__half, v.y));
                f.z = __half2float(__builtin_bit_cast(__half, v.z));
                f.w = __half2float(__builtin_bit_cast(__half, v.w));
            } else {
                f.x = __builtin_bit_cast(float, (unsigned int)v.x << 16);
                f.y = __builtin_bit_cast(float, (unsigned int)v.y << 16);
                f.z = __builtin_bit_cast(float, (unsigned int)v.z << 16);
                f.w = __builtin_bit_cast(float, (unsigned int)v.w << 16);
            }
            *reinterpret_cast<float4*>(&nrm[e >> 9][e & 511]) = f;
        }
    }

    __syncthreads();

    // ---- compute: wave w owns ksteps s = w*16 .. w*16+15 ----
    f32x4 acc0 = {0.f, 0.f, 0.f, 0.f};
    f32x4 acc1 = {0.f, 0.f, 0.f, 0.f};
    const int s0 = w * 16;

    #pragma unroll 4
    for (int i = 0; i < 16; ++i) {
        const int s = s0 + i;
        const int g = s * 4 + q;

        // B fragment: dequant one group in registers
        const unsigned int qv = qw[cl][g];
        const float n  = nrm[cl][g];
        const float av = n * 0.285714285714285714f;   // 2n/7
        union { unsigned short us[8]; short8 v; } B;
        #pragma unroll
        for (int e = 0; e < 8; ++e) {
            const float qf = (float)((qv >> (3 * e)) & 7u);
            B.us[e] = f2bf_u(fmaf(qf, av, -n));
        }

        // A fragments
        short8 A0, A1;
        if (PACKED) {
            A0 = *reinterpret_cast<const short8*>(&apk[(s * 64 + lane) * 8]);
            A1 = *reinterpret_cast<const short8*>(&apk[((128 + s) * 64 + lane) * 8]);
        } else {
            const int kg = s * 32 + q * 8;
            const float4 a0lo = *reinterpret_cast<const float4*>(&x[cl        * IN_F + kg]);
            const float4 a0hi = *reinterpret_cast<const float4*>(&x[cl        * IN_F + kg + 4]);
            const float4 a1lo = *reinterpret_cast<const float4*>(&x[(cl + 16) * IN_F + kg]);
            const float4 a1hi = *reinterpret_cast<const float4*>(&x[(cl + 16) * IN_F + kg + 4]);
            union { unsigned short us[8]; short8 v; } U0, U1;
            U0.us[0] = f2bf_u(a0lo.x); U0.us[1] = f2bf_u(a0lo.y);
            U0.us[2] = f2bf_u(a0lo.z); U0.us[3] = f2bf_u(a0lo.w);
            U0.us[4] = f2bf_u(a0hi.x); U0.us[5] = f2bf_u(a0hi.y);
            U0.us[6] = f2bf_u(a0hi.z); U0.us[7] = f2bf_u(a0hi.w);
            U1.us[0] = f2bf_u(a1lo.x); U1.us[1] = f2bf_u(a1lo.y);
            U1.us[2] = f2bf_u(a1lo.z); U1.us[3] = f2bf_u(a1lo.w);
            U1.us[4] = f2bf_u(a1hi.x); U1.us[5] = f2bf_u(a1hi.y);
            U1.us[6] = f2bf_u(a1hi.z); U1.us[7] = f2bf_u(a1hi.w);
            A0 = U0.v; A1 = U1.v;
        }

        acc0 = __builtin_amdgcn_mfma_f32_16x16x32_bf16(A0, B.v, acc0, 0, 0, 0);
        acc1 = __builtin_amdgcn_mfma_f32_16x16x32_bf16(A1, B.v, acc1, 0, 0, 0);
    }

    // ---- cross-wave K-reduction + bias + store ----
    #pragma unroll
    for (int i = 0; i < 4; ++i) {
        red[w][q * 4 + i][cl]      = acc0[i];
        red[w][16 + q * 4 + i][cl] = acc1[i];
    }
    __syncthreads();
    {
        const int m  = tid >> 4;   // 0..31
        const int nl = tid & 15;
        float ssum = 0.f;
        #pragma unroll
        for (int wv = 0; wv < NW; ++wv) ssum += red[wv][m][nl];
        out[m * OUT_F + nbase + nl] = ssum + bias[nbase + nl];
    }
}

extern "C" void kernel_launch(void* const* d_in, const int* in_sizes, int n_in,
                              void* d_out, int out_size, void* d_ws, size_t ws_size,
                              hipStream_t stream) {
    const float* x    = (const float*)d_in[0];
    const int*   wq3  = (const int*)d_in[1];
    const void*  wn   = (const void*)d_in[2];
    const float* bias = (const float*)d_in[3];
    float*       out  = (float*)d_out;

    if (ws_size >= (size_t)(2 * 128 * 64 * 8 * 2)) {   // 256 KB packed-A
        unsigned short* apk = (unsigned short*)d_ws;
        pack_x_kernel<<<dim3(32), dim3(512), 0, stream>>>(x, apk);
        l3b_main<true><<<dim3(OUT_F / BN), dim3(512), 0, stream>>>(x, wq3, wn, bias, out, apk);
    } else {
        l3b_main<false><<<dim3(OUT_F / BN), dim3(512), 0, stream>>>(x, wq3, wn, bias, out, nullptr);
    }
}